// Round 12
// baseline (100.346 us; speedup 1.0000x reference)
//
#include <hip/hip_runtime.h>

// RBCombiner: out[token] = sum of weighted dout_exp rows routed via indices.
// TOP_K = 2 (reference module constant) -> token = idx >> 1.
//
// Ledger (dur_us):
//   R2:  split CSR (5 nodes) + simple gather + cached             = 122.9
//   R3:  fused setup + 2-unroll + nt ld/st                        = 137.5
//   R4:  fused setup + 2-unroll + cached                          = 167.4
//   R6:  split CSR + simple gather + nt STORES                    = 111.4
//   R7:  bucket-direct (3 nodes: memset+bucket+gather)            =  99.8
//   R8:  R7 + nt row loads                                        =  99.9 (neutral)
//   R9:  cooperative 1-kernel fusion                              = 268.7 (abandoned)
//   R10: R8 + half-row gather (16384 blocks, 2 f32x4/thr)         =  97.5 <- best
// R10 confirmed a latency/issue component (gather ~5.1 TB/s logical vs
// 7.0 TB/s fill ceiling). R11: kill the per-iteration entry-load chain —
// ONE parallel 8B load (lane l holds entry l, n<=24<=64) + __shfl broadcast
// per iteration. Row loads across iterations become independent (max MLP).
// Single variable vs R10.
#define TOPK_SHIFT 1
#define BUCKET_CAP 24

typedef float f32x4 __attribute__((ext_vector_type(4)));

struct Entry { int src; float w; };   // 8 B, read as one dwordx2

// ---------------------------------------------------------------------------
// K1: route every entry directly into its token's bucket.
// Entry i in [0, S1+S2) corresponds to dout_exp row i.
//   i <  S1 : token = indices_s1[i] >> 1,                 w = weights[indices_s1[i]]
//   i >= S1 : j=i-S1; token = indices_s1[s1_to_s2[j]]>>1, w = weights[indices_s2[j]]
// ---------------------------------------------------------------------------
__global__ void bucket_kernel(
    const int* __restrict__ indices_s1,
    const int* __restrict__ indices_s2,
    const int* __restrict__ s1_to_s2,
    const float* __restrict__ weights,
    int S1, int NE,
    int* __restrict__ cursors,          // NT, pre-zeroed
    Entry* __restrict__ buckets)        // NT * BUCKET_CAP
{
    int i = blockIdx.x * blockDim.x + threadIdx.x;
    if (i >= NE) return;
    int token;
    float w;
    if (i < S1) {
        int idx = indices_s1[i];
        token = idx >> TOPK_SHIFT;
        w = weights[idx];
    } else {
        int j = i - S1;
        token = indices_s1[s1_to_s2[j]] >> TOPK_SHIFT;
        w = weights[indices_s2[j]];
    }
    int pos = atomicAdd(&cursors[token], 1);
    if (pos < BUCKET_CAP) {
        Entry e; e.src = i; e.w = w;
        buckets[token * BUCKET_CAP + pos] = e;
    }
}

// ---------------------------------------------------------------------------
// K2: half-row gather. TWO blocks per token (bid>>1 = token, bid&1 = half);
// each block's thread owns 2 f32x4 lanes (stride-256 interleave, 16 B/lane
// coalesced). Entry prefetch: lane l loads bucket entry l in ONE parallel
// 8B load; the e-loop broadcasts src/w via __shfl — no memory op on the
// address-dependence chain, so row loads across iterations are independent.
// NT row loads (R8: neutral) + NT stores (R6: -11.5us, RFO elimination).
// ---------------------------------------------------------------------------
__global__ __launch_bounds__(256) void gather_kernel(
    const f32x4* __restrict__ dout,      // (S1+S2) x D4
    const int*   __restrict__ cursors,   // NT (counts)
    const Entry* __restrict__ buckets,   // NT * BUCKET_CAP
    f32x4*       __restrict__ out,       // NT x D4
    int D4)
{
    const int bid  = blockIdx.x;
    const int t    = bid >> 1;           // token
    const int h    = bid & 1;            // which half of the row
    const int tid  = threadIdx.x;
    const int lane = tid & 63;
    int n = cursors[t];
    n = (n < BUCKET_CAP) ? n : BUCKET_CAP;
    const Entry* b = buckets + t * BUCKET_CAP;

    // One parallel entry load per wave: lane l holds entry l (l < n).
    Entry mine; mine.src = 0; mine.w = 0.0f;
    if (lane < n) mine = b[lane];

    if ((D4 & 1023) == 0) {
        // fast path: D4 multiple of 1024 (D=4096 -> one chunk). Block h
        // covers [chunk + h*512, +512) of each 1024-wide chunk.
        for (int chunk = 0; chunk < D4; chunk += 1024) {
            const int base = chunk + h * 512;
            f32x4 a0 = 0, a1 = 0;
            for (int e = 0; e < n; ++e) {
                const int   src = __shfl(mine.src, e);
                const float w   = __shfl(mine.w, e);
                const f32x4* row = dout + (size_t)src * (size_t)D4 + base;
                f32x4 v0 = __builtin_nontemporal_load(row + tid);
                f32x4 v1 = __builtin_nontemporal_load(row + tid + 256);
                a0 += w * v0;
                a1 += w * v1;
            }
            f32x4* orow = out + (size_t)t * (size_t)D4 + base;
            __builtin_nontemporal_store(a0, orow + tid);
            __builtin_nontemporal_store(a1, orow + tid + 256);
        }
    } else {
        // generic fallback (not hit for D=4096): half h covers its column range
        const int lo = (D4 * h) / 2;
        const int hi = (D4 * (h + 1)) / 2;
        for (int c = lo + tid; c < hi; c += 256) {
            f32x4 acc = 0;
            for (int e = 0; e < n; ++e) {
                const int   src = __shfl(mine.src, e);
                const float w   = __shfl(mine.w, e);
                acc += w * __builtin_nontemporal_load(
                           dout + (size_t)src * (size_t)D4 + c);
            }
            __builtin_nontemporal_store(acc, out + (size_t)t * (size_t)D4 + c);
        }
    }
}

// ---------------------------------------------------------------------------
// Launch. Inputs (setup_inputs order):
//   0: dout_exp (S1+S2, D) f32 | 1: weights (S1,) f32 | 2: indices_s1 (S1,)
//   3: indices_s2 (S2,) | 4: s1exp_to_s2_indices (S2,) | 5: n_tokens scalar
// ---------------------------------------------------------------------------
extern "C" void kernel_launch(void* const* d_in, const int* in_sizes, int n_in,
                              void* d_out, int out_size, void* d_ws, size_t ws_size,
                              hipStream_t stream) {
    const float* dout_exp   = (const float*)d_in[0];
    const float* weights    = (const float*)d_in[1];
    const int*   indices_s1 = (const int*)d_in[2];
    const int*   indices_s2 = (const int*)d_in[3];
    const int*   s1_to_s2   = (const int*)d_in[4];

    const int S1    = in_sizes[1];          // 16384
    const int S2    = in_sizes[3];          // 4096
    const int NROWS = S1 + S2;
    const int D     = in_sizes[0] / NROWS;  // 4096
    const int NT    = out_size / D;         // 8192
    const int D4    = D / 4;
    const int NE    = NROWS;                // 20480 entries

    // Workspace: cursors (NT ints, 32 KB) | buckets (NT*24*8 B = 1.5 MB)
    int*   cursors = (int*)d_ws;
    Entry* buckets = (Entry*)(cursors + NT);

    // Re-zero cursors every call (graph-replay safe).
    (void)hipMemsetAsync(cursors, 0, (size_t)NT * sizeof(int), stream);

    const int threads = 256;
    const int eblocks = (NE + threads - 1) / threads;

    bucket_kernel<<<eblocks, threads, 0, stream>>>(
        indices_s1, indices_s2, s1_to_s2, weights, S1, NE,
        cursors, buckets);

    gather_kernel<<<NT * 2, 256, 0, stream>>>(
        (const f32x4*)dout_exp, cursors, buckets,
        (f32x4*)d_out, D4);
}

// Round 13
// 97.442 us; speedup vs baseline: 1.0298x; 1.0298x over previous
//
#include <hip/hip_runtime.h>

// RBCombiner: out[token] = sum of weighted dout_exp rows routed via indices.
// TOP_K = 2 (reference module constant) -> token = idx >> 1.
//
// Ledger (dur_us):
//   R2:  split CSR (5 nodes) + simple gather + cached             = 122.9
//   R3:  fused setup + 2-unroll + nt ld/st                        = 137.5
//   R4:  fused setup + 2-unroll + cached                          = 167.4
//   R6:  split CSR + simple gather + nt STORES                    = 111.4
//   R7:  bucket-direct (3 nodes: memset+bucket+gather)            =  99.8
//   R8:  R7 + nt row loads                                        =  99.9 (neutral)
//   R9:  cooperative 1-kernel fusion                              = 268.7 (abandoned)
//   R10: R8 + half-row gather (16384 blocks, 2 f32x4/thr)         =  97.5 <- best
//   R11: R10 + wave-prefetch entries + __shfl broadcast           = 100.3 (REGRESSION:
//        ds_bpermute x2 per iter on issue path; entry load was already cheap)
// R12: pure revert to R10. Gather is scatter-BW-bound: 448 MB at ~5.05 TB/s
// (2 KB-chunk random gather + seq write = ~80% of the 6.3 TB/s copy ceiling,
// HBM row/channel efficiency — not addressable at HIP level). Setup+node
// boundaries ~8 us. Expect 97.5 +/- 1.5; then declare roofline.
#define TOPK_SHIFT 1
#define BUCKET_CAP 24

typedef float f32x4 __attribute__((ext_vector_type(4)));

struct Entry { int src; float w; };   // 8 B, read as one dwordx2

// ---------------------------------------------------------------------------
// K1: route every entry directly into its token's bucket.
// Entry i in [0, S1+S2) corresponds to dout_exp row i.
//   i <  S1 : token = indices_s1[i] >> 1,                 w = weights[indices_s1[i]]
//   i >= S1 : j=i-S1; token = indices_s1[s1_to_s2[j]]>>1, w = weights[indices_s2[j]]
// ---------------------------------------------------------------------------
__global__ void bucket_kernel(
    const int* __restrict__ indices_s1,
    const int* __restrict__ indices_s2,
    const int* __restrict__ s1_to_s2,
    const float* __restrict__ weights,
    int S1, int NE,
    int* __restrict__ cursors,          // NT, pre-zeroed
    Entry* __restrict__ buckets)        // NT * BUCKET_CAP
{
    int i = blockIdx.x * blockDim.x + threadIdx.x;
    if (i >= NE) return;
    int token;
    float w;
    if (i < S1) {
        int idx = indices_s1[i];
        token = idx >> TOPK_SHIFT;
        w = weights[idx];
    } else {
        int j = i - S1;
        token = indices_s1[s1_to_s2[j]] >> TOPK_SHIFT;
        w = weights[indices_s2[j]];
    }
    int pos = atomicAdd(&cursors[token], 1);
    if (pos < BUCKET_CAP) {
        Entry e; e.src = i; e.w = w;
        buckets[token * BUCKET_CAP + pos] = e;
    }
}

// ---------------------------------------------------------------------------
// K2: half-row gather. TWO blocks per token (bid>>1 = token, bid&1 = half);
// each block's thread owns 2 f32x4 lanes (stride-256 interleave, 16 B/lane
// coalesced). 2x independent block pipelines vs full-row (cold-start chains
// overlap, tail stragglers halve). NT row loads (R8: neutral, kept) and NT
// stores (R6: -11.5us, intra-call RFO elimination). Entry/cursor loads
// cached (tiny, L2-resident).
// ---------------------------------------------------------------------------
__global__ __launch_bounds__(256) void gather_kernel(
    const f32x4* __restrict__ dout,      // (S1+S2) x D4
    const int*   __restrict__ cursors,   // NT (counts)
    const Entry* __restrict__ buckets,   // NT * BUCKET_CAP
    f32x4*       __restrict__ out,       // NT x D4
    int D4)
{
    const int bid = blockIdx.x;
    const int t   = bid >> 1;            // token
    const int h   = bid & 1;             // which half of the row
    const int tid = threadIdx.x;
    int n = cursors[t];
    n = (n < BUCKET_CAP) ? n : BUCKET_CAP;
    const Entry* b = buckets + t * BUCKET_CAP;

    if ((D4 & 1023) == 0) {
        // fast path: D4 multiple of 1024 (D=4096 -> one chunk). Block h
        // covers [chunk + h*512, +512) of each 1024-wide chunk.
        for (int chunk = 0; chunk < D4; chunk += 1024) {
            const int base = chunk + h * 512;
            f32x4 a0 = 0, a1 = 0;
            for (int e = 0; e < n; ++e) {
                const Entry en = b[e];                 // 8B broadcast load
                const float w = en.w;
                const f32x4* row = dout + (size_t)en.src * (size_t)D4 + base;
                f32x4 v0 = __builtin_nontemporal_load(row + tid);
                f32x4 v1 = __builtin_nontemporal_load(row + tid + 256);
                a0 += w * v0;
                a1 += w * v1;
            }
            f32x4* orow = out + (size_t)t * (size_t)D4 + base;
            __builtin_nontemporal_store(a0, orow + tid);
            __builtin_nontemporal_store(a1, orow + tid + 256);
        }
    } else {
        // generic fallback (not hit for D=4096): half h covers its column range
        const int lo = (D4 * h) / 2;
        const int hi = (D4 * (h + 1)) / 2;
        for (int c = lo + tid; c < hi; c += 256) {
            f32x4 acc = 0;
            for (int e = 0; e < n; ++e)
                acc += b[e].w * __builtin_nontemporal_load(
                           dout + (size_t)b[e].src * (size_t)D4 + c);
            __builtin_nontemporal_store(acc, out + (size_t)t * (size_t)D4 + c);
        }
    }
}

// ---------------------------------------------------------------------------
// Launch. Inputs (setup_inputs order):
//   0: dout_exp (S1+S2, D) f32 | 1: weights (S1,) f32 | 2: indices_s1 (S1,)
//   3: indices_s2 (S2,) | 4: s1exp_to_s2_indices (S2,) | 5: n_tokens scalar
// ---------------------------------------------------------------------------
extern "C" void kernel_launch(void* const* d_in, const int* in_sizes, int n_in,
                              void* d_out, int out_size, void* d_ws, size_t ws_size,
                              hipStream_t stream) {
    const float* dout_exp   = (const float*)d_in[0];
    const float* weights    = (const float*)d_in[1];
    const int*   indices_s1 = (const int*)d_in[2];
    const int*   indices_s2 = (const int*)d_in[3];
    const int*   s1_to_s2   = (const int*)d_in[4];

    const int S1    = in_sizes[1];          // 16384
    const int S2    = in_sizes[3];          // 4096
    const int NROWS = S1 + S2;
    const int D     = in_sizes[0] / NROWS;  // 4096
    const int NT    = out_size / D;         // 8192
    const int D4    = D / 4;
    const int NE    = NROWS;                // 20480 entries

    // Workspace: cursors (NT ints, 32 KB) | buckets (NT*24*8 B = 1.5 MB)
    int*   cursors = (int*)d_ws;
    Entry* buckets = (Entry*)(cursors + NT);

    // Re-zero cursors every call (graph-replay safe).
    (void)hipMemsetAsync(cursors, 0, (size_t)NT * sizeof(int), stream);

    const int threads = 256;
    const int eblocks = (NE + threads - 1) / threads;

    bucket_kernel<<<eblocks, threads, 0, stream>>>(
        indices_s1, indices_s2, s1_to_s2, weights, S1, NE,
        cursors, buckets);

    gather_kernel<<<NT * 2, 256, 0, stream>>>(
        (const f32x4*)dout_exp, cursors, buckets,
        (f32x4*)d_out, D4);
}